// Round 2
// baseline (205.051 us; speedup 1.0000x reference)
//
#include <hip/hip_runtime.h>
#include <hip/hip_bf16.h>
#include <stdint.h>
#include <stddef.h>

// ContrastiveLoss: N=4096, D=768.
// loss = mean_{ij} (1-g)*d2 + g*max(2-sqrt(d2),0)^2,
// d2 = sa[i]+sb[j]-2*dot(i,j)+2e-6*(ra[i]-rb[j])+768e-12 (clamped at 0).
// R1: BK=64 + exact 8-col XOR swizzle (conflict-free ds_read_b128),
//     gt bit-packed to u64 (2 MB, L2-resident), float4 prep.

#define NROWS 4096
#define DIM   768
#define BM    128
#define BN    128
#define BK    64
#define MARGIN 2.0f
#define EPSV   1e-6f

typedef __bf16 bf16_t;
typedef bf16_t bf16x8 __attribute__((ext_vector_type(8)));
typedef bf16_t bf16x4 __attribute__((ext_vector_type(4)));
typedef float  f32x4  __attribute__((ext_vector_type(4)));

// ---------------- prep: bf16 cast + exact row sums / sum-of-squares ---------
// One wave per row; lane reads 3 float4 (12 floats), stores 3 bf16x4.
__global__ __launch_bounds__(256) void prep_kernel(
    const float* __restrict__ A, const float* __restrict__ B,
    bf16_t* __restrict__ Ab, bf16_t* __restrict__ Bb,
    float* __restrict__ sa, float* __restrict__ sb,
    float* __restrict__ ra, float* __restrict__ rb)
{
    const int tid  = threadIdx.x;
    const int wave = tid >> 6;
    const int lane = tid & 63;
    const int row  = blockIdx.x * 4 + wave;
    const int isB  = blockIdx.y;
    const float* X = isB ? B : A;
    bf16_t* Xb     = isB ? Bb : Ab;
    float* sdst    = isB ? sb : sa;
    float* rdst    = isB ? rb : ra;

    const float4* xr = (const float4*)(X + (size_t)row * DIM);
    bf16x4* xb = (bf16x4*)(Xb + (size_t)row * DIM);

    float sum = 0.0f, sq = 0.0f;
    #pragma unroll
    for (int j = 0; j < 3; ++j) {
        float4 v = xr[lane + 64 * j];
        bf16x4 o;
        o[0] = (bf16_t)v.x; o[1] = (bf16_t)v.y;
        o[2] = (bf16_t)v.z; o[3] = (bf16_t)v.w;
        xb[lane + 64 * j] = o;
        sum += (v.x + v.y) + (v.z + v.w);
        sq  += v.x * v.x + v.y * v.y + v.z * v.z + v.w * v.w;
    }
    #pragma unroll
    for (int off = 32; off > 0; off >>= 1) {
        sum += __shfl_down(sum, off);
        sq  += __shfl_down(sq,  off);
    }
    if (lane == 0) { rdst[row] = sum; sdst[row] = sq; }
}

// ---------------- pack: gt int32 (0/1) -> u64 bitmask per 64-col block ------
// bit c of word [row][cb] = gt[row][cb*64+c]. One word per wave per iter.
__global__ __launch_bounds__(256) void pack_kernel(
    const int* __restrict__ gt, unsigned long long* __restrict__ gtp)
{
    const int lane = threadIdx.x & 63;
    const int wid  = blockIdx.x * 4 + (threadIdx.x >> 6); // 512*4 = 2048 waves
    const size_t base = (size_t)wid * 128;                // words per wave
    #pragma unroll 4
    for (int i = 0; i < 128; ++i) {
        const int v = gt[(base + i) * 64 + lane];
        const unsigned long long m = __ballot(v != 0);
        if (lane == 0) gtp[base + i] = m;
    }
}

// ---------------- fused GEMM + loss ----------------------------------------
// 128x128 tile / 256 threads (4 waves x 64x64 of 4x4 16x16x32 MFMA), BK=64,
// global_load_lds width 16, XOR-8 swizzled LDS (conflict-free b128 reads).
__global__ __launch_bounds__(256, 4) void loss_kernel(
    const bf16_t* __restrict__ A, const bf16_t* __restrict__ B,
    const float* __restrict__ sa, const float* __restrict__ sb,
    const float* __restrict__ ra, const float* __restrict__ rb,
    const uint2* __restrict__ gtp, float* __restrict__ out)
{
    __shared__ __align__(16) bf16_t As[BM * BK];  // 16 KB
    __shared__ __align__(16) bf16_t Bs[BN * BK];  // 16 KB
    __shared__ float redp[4];

    const int tid  = threadIdx.x;
    const int wave = tid >> 6;
    const int lane = tid & 63;
    const int m0 = blockIdx.y * BM;
    const int n0 = blockIdx.x * BN;

    f32x4 acc[4][4] = {};

    // staging: lane -> row lrow (of 8), fetches global chunk gc so that LDS
    // position (lane&7) holds chunk ((lane&7) ^ (row&7))  [XOR-8 swizzle]
    const int lrow = lane >> 3;          // 0..7
    const int gc   = (lane & 7) ^ lrow;  // global k-chunk (8 bf16 = 16 B)

    const int fr = lane & 15;            // frag row (A) / frag col (B)
    const int q  = lane >> 4;            // k-quad within 32-wide MFMA window
    const int wm = (wave >> 1) * 64;
    const int wn = (wave & 1) * 64;

    for (int k0 = 0; k0 < DIM; k0 += BK) {
        __syncthreads();   // prev iter's LDS reads done
        #pragma unroll
        for (int s = 0; s < 4; ++s) {
            const int rowbase = s * 32 + wave * 8;          // wave-uniform
            const int grow    = rowbase + lrow;
            const bf16_t* ga = A + (size_t)(m0 + grow) * DIM + k0 + gc * 8;
            const bf16_t* gb = B + (size_t)(n0 + grow) * DIM + k0 + gc * 8;
            __builtin_amdgcn_global_load_lds(
                (const __attribute__((address_space(1))) void*)ga,
                (__attribute__((address_space(3))) void*)(As + rowbase * BK),
                16, 0, 0);
            __builtin_amdgcn_global_load_lds(
                (const __attribute__((address_space(1))) void*)gb,
                (__attribute__((address_space(3))) void*)(Bs + rowbase * BK),
                16, 0, 0);
        }
        __syncthreads();   // staging complete

        #pragma unroll
        for (int kk = 0; kk < 2; ++kk) {
            bf16x8 af[4], bfr[4];
            const int c = kk * 4 + q;                 // chunk within BK
            #pragma unroll
            for (int i = 0; i < 4; ++i) {
                const int pos = (c ^ (fr & 7)) * 8;
                af[i]  = *(const bf16x8*)(As + (wm + i * 16 + fr) * BK + pos);
                bfr[i] = *(const bf16x8*)(Bs + (wn + i * 16 + fr) * BK + pos);
            }
            #pragma unroll
            for (int mi = 0; mi < 4; ++mi)
                #pragma unroll
                for (int ni = 0; ni < 4; ++ni)
                    acc[mi][ni] = __builtin_amdgcn_mfma_f32_16x16x32_bf16(
                        af[mi], bfr[ni], acc[mi][ni], 0, 0, 0);
        }
    }

    // ---- fused epilogue: C/D layout col=lane&15, row=(lane>>4)*4+reg ----
    const int cq = lane & 15;
    const int rq = (lane >> 4) * 4;
    const int cb = (n0 + wn) >> 6;   // 64-col block index for packed gt

    float sbv[4], rbv[4];
    #pragma unroll
    for (int ni = 0; ni < 4; ++ni) {
        const int col = n0 + wn + ni * 16 + cq;
        sbv[ni] = sb[col];
        rbv[ni] = rb[col];
    }

    float local = 0.0f;
    #pragma unroll
    for (int mi = 0; mi < 4; ++mi) {
        #pragma unroll
        for (int rr = 0; rr < 4; ++rr) {
            const int row = m0 + wm + mi * 16 + rq + rr;
            const float sav = sa[row];
            const float rav = ra[row];
            const uint2 w = gtp[(size_t)row * (NROWS / 64) + cb];
            #pragma unroll
            for (int ni = 0; ni < 4; ++ni) {
                const float dot = acc[mi][ni][rr];
                float sqv = sav + sbv[ni] - 2.0f * dot
                          + (2.0f * EPSV) * (rav - rbv[ni])
                          + (float)DIM * EPSV * EPSV;
                float msq  = fmaxf(sqv, 0.0f);
                float dist = sqrtf(msq);
                float h    = fmaxf(MARGIN - dist, 0.0f);
                const unsigned wd = (ni < 2) ? w.x : w.y;
                const unsigned g  = (wd >> (cq + (ni & 1) * 16)) & 1u;
                local += g ? (h * h) : msq;
            }
        }
    }

    #pragma unroll
    for (int off = 32; off > 0; off >>= 1) local += __shfl_down(local, off);
    if (lane == 0) redp[wave] = local;
    __syncthreads();
    if (tid == 0) {
        const float s = (redp[0] + redp[1]) + (redp[2] + redp[3]);
        atomicAdd(out, s * (1.0f / (4096.0f * 4096.0f)));
    }
}

// ---------------------------------------------------------------------------
extern "C" void kernel_launch(void* const* d_in, const int* in_sizes, int n_in,
                              void* d_out, int out_size, void* d_ws, size_t ws_size,
                              hipStream_t stream)
{
    const float* A  = (const float*)d_in[0];
    const float* B  = (const float*)d_in[1];
    const int*   gt = (const int*)d_in[2];
    float* out = (float*)d_out;

    char* ws = (char*)d_ws;
    const size_t NB = (size_t)NROWS * DIM * sizeof(bf16_t); // 6,291,456
    bf16_t* Ab = (bf16_t*)(ws);
    bf16_t* Bb = (bf16_t*)(ws + NB);
    float* sa = (float*)(ws + 2 * NB);
    float* sb = (float*)(ws + 2 * NB + 16384);
    float* ra = (float*)(ws + 2 * NB + 32768);
    float* rb = (float*)(ws + 2 * NB + 49152);
    unsigned long long* gtp = (unsigned long long*)(ws + 2 * NB + 65536); // 2 MB

    hipMemsetAsync(d_out, 0, sizeof(float) * (size_t)out_size, stream);
    prep_kernel<<<dim3(NROWS / 4, 2), 256, 0, stream>>>(A, B, Ab, Bb, sa, sb, ra, rb);
    pack_kernel<<<dim3(512), 256, 0, stream>>>(gt, gtp);
    loss_kernel<<<dim3(NROWS / BN, NROWS / BM), 256, 0, stream>>>(
        Ab, Bb, sa, sb, ra, rb, (const uint2*)gtp, out);
}

// Round 3
// 147.894 us; speedup vs baseline: 1.3865x; 1.3865x over previous
//
#include <hip/hip_runtime.h>
#include <hip/hip_bf16.h>
#include <stdint.h>
#include <stddef.h>

// ContrastiveLoss: N=4096, D=768.
// loss = mean_{ij} (1-g)*d2 + g*max(2-sqrt(d2),0)^2,
// d2 = sa[i]+sb[j]-2*dot(i,j)+2e-6*(ra[i]-rb[j])+768e-12 (clamped at 0).
// R2: fused prologue (prep + wide-ILP gt pack + out zeroing, 1 dispatch),
//     loss kernel unchanged (BK=64, XOR-8 swizzle, packed-gt epilogue).

#define NROWS 4096
#define DIM   768
#define BM    128
#define BN    128
#define BK    64
#define MARGIN 2.0f
#define EPSV   1e-6f

typedef __bf16 bf16_t;
typedef bf16_t bf16x8 __attribute__((ext_vector_type(8)));
typedef bf16_t bf16x4 __attribute__((ext_vector_type(4)));
typedef float  f32x4  __attribute__((ext_vector_type(4)));
typedef unsigned long long u64;

// ---------------- prologue: prep (2048 blocks) + pack (8192 blocks) --------
// prep: one wave per row; lane reads 3 float4, stores 3 bf16x4, reduces
//       row sum / sum-of-squares exactly in fp32.
// pack: one wave packs 8 u64 words; 8 independent coalesced 256-B loads
//       into regs, then 8 ballots, one coalesced 64-B store (lanes 0-7).
__global__ __launch_bounds__(256) void prologue_kernel(
    const float* __restrict__ A, const float* __restrict__ B,
    const int* __restrict__ gt,
    bf16_t* __restrict__ Ab, bf16_t* __restrict__ Bb,
    float* __restrict__ sa, float* __restrict__ sb,
    float* __restrict__ ra, float* __restrict__ rb,
    u64* __restrict__ gtp, float* __restrict__ out)
{
    const int tid  = threadIdx.x;
    const int wave = tid >> 6;
    const int lane = tid & 63;
    const int bx   = blockIdx.x;

    if (bx == 0 && tid == 0) out[0] = 0.0f;   // replaces hipMemsetAsync

    if (bx < 2048) {
        // ---- prep role ----
        const int isB  = bx >= 1024;
        const int row  = (bx & 1023) * 4 + wave;
        const float* X = isB ? B : A;
        bf16_t* Xb     = isB ? Bb : Ab;
        float* sdst    = isB ? sb : sa;
        float* rdst    = isB ? rb : ra;

        const float4* xr = (const float4*)(X + (size_t)row * DIM);
        bf16x4* xb = (bf16x4*)(Xb + (size_t)row * DIM);

        float sum = 0.0f, sq = 0.0f;
        #pragma unroll
        for (int j = 0; j < 3; ++j) {
            float4 v = xr[lane + 64 * j];
            bf16x4 o;
            o[0] = (bf16_t)v.x; o[1] = (bf16_t)v.y;
            o[2] = (bf16_t)v.z; o[3] = (bf16_t)v.w;
            xb[lane + 64 * j] = o;
            sum += (v.x + v.y) + (v.z + v.w);
            sq  += v.x * v.x + v.y * v.y + v.z * v.z + v.w * v.w;
        }
        #pragma unroll
        for (int off = 32; off > 0; off >>= 1) {
            sum += __shfl_down(sum, off);
            sq  += __shfl_down(sq,  off);
        }
        if (lane == 0) { rdst[row] = sum; sdst[row] = sq; }
    } else {
        // ---- pack role: 8192 blocks x 4 waves x 8 words = 262144 words ----
        const int wid = (bx - 2048) * 4 + wave;
        const size_t base = (size_t)wid * 8;          // first word index
        int v[8];
        #pragma unroll
        for (int i = 0; i < 8; ++i)
            v[i] = gt[base * 64 + (size_t)i * 64 + lane];
        u64 mine = 0;
        #pragma unroll
        for (int i = 0; i < 8; ++i) {
            const u64 m = __ballot(v[i] != 0);
            if (lane == i) mine = m;
        }
        if (lane < 8) gtp[base + lane] = mine;
    }
}

// ---------------- fused GEMM + loss ----------------------------------------
// 128x128 tile / 256 threads (4 waves x 64x64 of 4x4 16x16x32 MFMA), BK=64,
// global_load_lds width 16, XOR-8 swizzled LDS (conflict-free b128 reads).
__global__ __launch_bounds__(256, 4) void loss_kernel(
    const bf16_t* __restrict__ A, const bf16_t* __restrict__ B,
    const float* __restrict__ sa, const float* __restrict__ sb,
    const float* __restrict__ ra, const float* __restrict__ rb,
    const uint2* __restrict__ gtp, float* __restrict__ out)
{
    __shared__ __align__(16) bf16_t As[BM * BK];  // 16 KB
    __shared__ __align__(16) bf16_t Bs[BN * BK];  // 16 KB
    __shared__ float redp[4];

    const int tid  = threadIdx.x;
    const int wave = tid >> 6;
    const int lane = tid & 63;
    const int m0 = blockIdx.y * BM;
    const int n0 = blockIdx.x * BN;

    f32x4 acc[4][4] = {};

    // staging: lane -> row lrow (of 8), fetches global chunk gc so that LDS
    // position (lane&7) holds chunk ((lane&7) ^ (row&7))  [XOR-8 swizzle]
    const int lrow = lane >> 3;          // 0..7
    const int gc   = (lane & 7) ^ lrow;  // global k-chunk (8 bf16 = 16 B)

    const int fr = lane & 15;            // frag row (A) / frag col (B)
    const int q  = lane >> 4;            // k-quad within 32-wide MFMA window
    const int wm = (wave >> 1) * 64;
    const int wn = (wave & 1) * 64;

    for (int k0 = 0; k0 < DIM; k0 += BK) {
        __syncthreads();   // prev iter's LDS reads done
        #pragma unroll
        for (int s = 0; s < 4; ++s) {
            const int rowbase = s * 32 + wave * 8;          // wave-uniform
            const int grow    = rowbase + lrow;
            const bf16_t* ga = A + (size_t)(m0 + grow) * DIM + k0 + gc * 8;
            const bf16_t* gb = B + (size_t)(n0 + grow) * DIM + k0 + gc * 8;
            __builtin_amdgcn_global_load_lds(
                (const __attribute__((address_space(1))) void*)ga,
                (__attribute__((address_space(3))) void*)(As + rowbase * BK),
                16, 0, 0);
            __builtin_amdgcn_global_load_lds(
                (const __attribute__((address_space(1))) void*)gb,
                (__attribute__((address_space(3))) void*)(Bs + rowbase * BK),
                16, 0, 0);
        }
        __syncthreads();   // staging complete

        #pragma unroll
        for (int kk = 0; kk < 2; ++kk) {
            bf16x8 af[4], bfr[4];
            const int c = kk * 4 + q;                 // chunk within BK
            #pragma unroll
            for (int i = 0; i < 4; ++i) {
                const int pos = (c ^ (fr & 7)) * 8;
                af[i]  = *(const bf16x8*)(As + (wm + i * 16 + fr) * BK + pos);
                bfr[i] = *(const bf16x8*)(Bs + (wn + i * 16 + fr) * BK + pos);
            }
            #pragma unroll
            for (int mi = 0; mi < 4; ++mi)
                #pragma unroll
                for (int ni = 0; ni < 4; ++ni)
                    acc[mi][ni] = __builtin_amdgcn_mfma_f32_16x16x32_bf16(
                        af[mi], bfr[ni], acc[mi][ni], 0, 0, 0);
        }
    }

    // ---- fused epilogue: C/D layout col=lane&15, row=(lane>>4)*4+reg ----
    const int cq = lane & 15;
    const int rq = (lane >> 4) * 4;
    const int cb = (n0 + wn) >> 6;   // 64-col block index for packed gt

    float sbv[4], rbv[4];
    #pragma unroll
    for (int ni = 0; ni < 4; ++ni) {
        const int col = n0 + wn + ni * 16 + cq;
        sbv[ni] = sb[col];
        rbv[ni] = rb[col];
    }

    float local = 0.0f;
    #pragma unroll
    for (int mi = 0; mi < 4; ++mi) {
        #pragma unroll
        for (int rr = 0; rr < 4; ++rr) {
            const int row = m0 + wm + mi * 16 + rq + rr;
            const float sav = sa[row];
            const float rav = ra[row];
            const uint2 w = gtp[(size_t)row * (NROWS / 64) + cb];
            #pragma unroll
            for (int ni = 0; ni < 4; ++ni) {
                const float dot = acc[mi][ni][rr];
                float sqv = sav + sbv[ni] - 2.0f * dot
                          + (2.0f * EPSV) * (rav - rbv[ni])
                          + (float)DIM * EPSV * EPSV;
                float msq  = fmaxf(sqv, 0.0f);
                float dist = sqrtf(msq);
                float h    = fmaxf(MARGIN - dist, 0.0f);
                const unsigned wd = (ni < 2) ? w.x : w.y;
                const unsigned g  = (wd >> (cq + (ni & 1) * 16)) & 1u;
                local += g ? (h * h) : msq;
            }
        }
    }

    #pragma unroll
    for (int off = 32; off > 0; off >>= 1) local += __shfl_down(local, off);
    if (lane == 0) redp[wave] = local;
    __syncthreads();
    if (tid == 0) {
        const float s = (redp[0] + redp[1]) + (redp[2] + redp[3]);
        atomicAdd(out, s * (1.0f / (4096.0f * 4096.0f)));
    }
}

// ---------------------------------------------------------------------------
extern "C" void kernel_launch(void* const* d_in, const int* in_sizes, int n_in,
                              void* d_out, int out_size, void* d_ws, size_t ws_size,
                              hipStream_t stream)
{
    const float* A  = (const float*)d_in[0];
    const float* B  = (const float*)d_in[1];
    const int*   gt = (const int*)d_in[2];
    float* out = (float*)d_out;

    char* ws = (char*)d_ws;
    const size_t NB = (size_t)NROWS * DIM * sizeof(bf16_t); // 6,291,456
    bf16_t* Ab = (bf16_t*)(ws);
    bf16_t* Bb = (bf16_t*)(ws + NB);
    float* sa = (float*)(ws + 2 * NB);
    float* sb = (float*)(ws + 2 * NB + 16384);
    float* ra = (float*)(ws + 2 * NB + 32768);
    float* rb = (float*)(ws + 2 * NB + 49152);
    u64* gtp  = (u64*)(ws + 2 * NB + 65536); // 2 MB

    // 2048 prep blocks + 8192 pack blocks in one dispatch
    prologue_kernel<<<dim3(10240), 256, 0, stream>>>(
        A, B, gt, Ab, Bb, sa, sb, ra, rb, gtp, out);
    loss_kernel<<<dim3(NROWS / BN, NROWS / BM), 256, 0, stream>>>(
        Ab, Bb, sa, sb, ra, rb, (const uint2*)gtp, out);
}